// Round 6
// baseline (882.529 us; speedup 1.0000x reference)
//
#include <hip/hip_runtime.h>
#include <stdint.h>

typedef unsigned short u16;
typedef unsigned int   u32;
typedef __attribute__((ext_vector_type(8))) __bf16 bf16x8;
typedef __attribute__((ext_vector_type(4))) float  f32x4;

__device__ __forceinline__ float bflo(u32 u){ return __uint_as_float(u << 16); }
__device__ __forceinline__ float bfhi(u32 u){ return __uint_as_float(u & 0xffff0000u); }
__device__ __forceinline__ float bf2f(u16 v){ return __uint_as_float(((u32)v) << 16); }
__device__ __forceinline__ u16 f2bf(float f){ u32 u = __float_as_uint(f);
    return (u16)((u + 0x7fffu + ((u >> 16) & 1u)) >> 16); }
__device__ __forceinline__ u32 pack2(float a, float b){ return (u32)f2bf(a) | ((u32)f2bf(b) << 16); }

union ABu { f32x4 f; bf16x8 b; };
__device__ __forceinline__ bf16x8 ldfrag(const u16* p){ ABu u; u.f = *(const f32x4*)p; return u.b; }

// ---------------- zero fill (zbuf: 512 B of zeros for masked rows) ----------
__global__ void zero_kernel(u32* p){ p[threadIdx.x] = 0u; }

// -------- transpose one weight: fp32 [R,256] -> bf16 [256,R] ----------------
__global__ __launch_bounds__(256)
void transpose_one(const float* __restrict__ in, u16* __restrict__ out, int R)
{
    const int r0 = blockIdx.y * 32, c0 = blockIdx.x * 32;
    __shared__ u16 t[32][33];
    const int tx = threadIdx.x & 31, ty = threadIdx.x >> 5;
    #pragma unroll
    for (int i = 0; i < 4; ++i)
        t[ty + i*8][tx] = f2bf(in[(size_t)(r0 + ty + i*8) * 256 + c0 + tx]);
    __syncthreads();
    #pragma unroll
    for (int i = 0; i < 4; ++i)
        out[(size_t)(c0 + ty + i*8) * R + r0 + tx] = t[tx][ty + i*8];
}

// -------- group norm (per sample, per group) + SiLU; IF32 = fp32 input ------
template<int C, int CPG, int IF32>
__global__ __launch_bounds__(256)
void gn_silu_kernel(const void* __restrict__ xv, const float* __restrict__ gw,
                    const float* __restrict__ gb, u16* __restrict__ y)
{
    const int b = blockIdx.x >> 5, g = blockIdx.x & 31;
    const size_t base = (size_t)b * 4096 * C + g * CPG;
    float s = 0.f, ss = 0.f;
    for (int p = threadIdx.x; p < 4096; p += 256) {
        if constexpr (IF32) {
            const float* rp = (const float*)xv + base + (size_t)p * C;
            #pragma unroll
            for (int c = 0; c < CPG; ++c) { const float v = rp[c]; s += v; ss += v*v; }
        } else {
            const u32* rp = (const u32*)((const u16*)xv + base + (size_t)p * C);
            #pragma unroll
            for (int c = 0; c < CPG/2; ++c) {
                const u32 u = rp[c];
                const float v0 = bflo(u), v1 = bfhi(u);
                s += v0 + v1; ss += v0*v0 + v1*v1;
            }
        }
    }
    __shared__ float sbuf[8];
    const int wave = threadIdx.x >> 6, lane = threadIdx.x & 63;
    #pragma unroll
    for (int o = 32; o > 0; o >>= 1) { s += __shfl_down(s, o); ss += __shfl_down(ss, o); }
    if (lane == 0) { sbuf[wave] = s; sbuf[4 + wave] = ss; }
    __syncthreads();
    s  = sbuf[0] + sbuf[1] + sbuf[2] + sbuf[3];
    ss = sbuf[4] + sbuf[5] + sbuf[6] + sbuf[7];
    constexpr float invn = 1.f / (4096.f * CPG);
    const float mean = s * invn;
    const float rstd = rsqrtf(ss * invn - mean * mean + 1e-5f);
    float ga[CPG], be[CPG];
    #pragma unroll
    for (int c = 0; c < CPG; ++c) { ga[c] = gw[g*CPG + c] * rstd; be[c] = gb[g*CPG + c]; }
    for (int p = threadIdx.x; p < 4096; p += 256) {
        u32* wp = (u32*)(y + base + (size_t)p * C);
        float v[CPG];
        if constexpr (IF32) {
            const float* rp = (const float*)xv + base + (size_t)p * C;
            #pragma unroll
            for (int c = 0; c < CPG; ++c) v[c] = rp[c];
        } else {
            const u32* rp = (const u32*)((const u16*)xv + base + (size_t)p * C);
            #pragma unroll
            for (int c = 0; c < CPG/2; ++c) { const u32 u = rp[c]; v[2*c] = bflo(u); v[2*c+1] = bfhi(u); }
        }
        #pragma unroll
        for (int c = 0; c < CPG/2; ++c) {
            float v0 = (v[2*c]   - mean) * ga[2*c]   + be[2*c];
            float v1 = (v[2*c+1] - mean) * ga[2*c+1] + be[2*c+1];
            v0 = v0 / (1.f + __expf(-v0));
            v1 = v1 / (1.f + __expf(-v1));
            wp[c] = pack2(v0, v1);
        }
    }
}

// ---------------- layer norm (fp32 in, fp32 params) -> bf16 out -------------
__global__ __launch_bounds__(256)
void ln_kernel(const float* __restrict__ h, const float* __restrict__ w,
               const float* __restrict__ b, u16* __restrict__ y)
{
    const int row = blockIdx.x * 4 + (threadIdx.x >> 6);
    const int lane = threadIdx.x & 63;
    const f32x4 v = *(const f32x4*)(h + (size_t)row * 256 + lane * 4);
    float s  = v[0] + v[1] + v[2] + v[3];
    float ss = v[0]*v[0] + v[1]*v[1] + v[2]*v[2] + v[3]*v[3];
    #pragma unroll
    for (int o = 32; o > 0; o >>= 1) { s += __shfl_down(s, o); ss += __shfl_down(ss, o); }
    s = __shfl(s, 0); ss = __shfl(ss, 0);
    const float mean = s * (1.f/256.f);
    const float rstd = rsqrtf(ss * (1.f/256.f) - mean*mean + 1e-5f);
    const int c = lane * 4;
    const float o0 = (v[0]-mean)*rstd*w[c+0] + b[c+0];
    const float o1 = (v[1]-mean)*rstd*w[c+1] + b[c+1];
    const float o2 = (v[2]-mean)*rstd*w[c+2] + b[c+2];
    const float o3 = (v[3]-mean)*rstd*w[c+3] + b[c+3];
    u32* wp = (u32*)(y + (size_t)row * 256 + c);
    wp[0] = pack2(o0, o1); wp[1] = pack2(o2, o3);
}

// -------- cross attention: block = (h, b, p-chunk of 512 rows) --------------
__global__ __launch_bounds__(256)
void attn_kernel(const u16* __restrict__ q, const float* __restrict__ kf,
                 const float* __restrict__ vf, u16* __restrict__ o)
{
    const int h = blockIdx.x, b = blockIdx.y, pc = blockIdx.z;
    __shared__ float kS[77*16], vS[77*16];
    for (int i = threadIdx.x; i < 77*16; i += 256) {
        const int l = i >> 4, d = i & 15;
        const size_t src = (size_t)(b*77 + l) * 256 + h*16 + d;
        kS[i] = kf[src];
        vS[i] = vf[src];
    }
    __syncthreads();
    for (int p = pc*512 + threadIdx.x; p < pc*512 + 512; p += 256) {
        const size_t row = (size_t)b * 4096 + p;
        const u32* qp = (const u32*)(q + row * 256 + h * 16);
        float qv[16];
        #pragma unroll
        for (int d2 = 0; d2 < 8; ++d2) { const u32 u = qp[d2]; qv[2*d2] = bflo(u); qv[2*d2+1] = bfhi(u); }
        float m = -1e30f;
        for (int l = 0; l < 77; ++l) {
            float sc = 0.f;
            #pragma unroll
            for (int d = 0; d < 16; ++d) sc += qv[d] * kS[l*16 + d];
            m = fmaxf(m, sc);
        }
        float ssum = 0.f, oacc[16];
        #pragma unroll
        for (int d = 0; d < 16; ++d) oacc[d] = 0.f;
        for (int l = 0; l < 77; ++l) {
            float sc = 0.f;
            #pragma unroll
            for (int d = 0; d < 16; ++d) sc += qv[d] * kS[l*16 + d];
            const float pw = __expf((sc - m) * 0.25f);   // 1/sqrt(16)
            ssum += pw;
            #pragma unroll
            for (int d = 0; d < 16; ++d) oacc[d] += pw * vS[l*16 + d];
        }
        const float inv = 1.f / ssum;
        u32* op = (u32*)(o + row * 256 + h * 16);
        #pragma unroll
        for (int d2 = 0; d2 < 8; ++d2) op[d2] = pack2(oacc[2*d2]*inv, oacc[2*d2+1]*inv);
    }
}

// ---------------- MFMA GEMM: C[M,256] = A[M,Ktot] @ Bt[256,Ktot]^T ----------
// GATHER: A row for K-block comes from bf16 A[neigh[m][k0/CIN]*CIN + k0%CIN];
// invalid idx -> zbuf. AF32: A is fp32, converted to bf16 during staging.
// OMODE: 0 = bf16 out; 1 = fp32 out; 2 = fp32 out + bf16 out2.
// RES: add fp32 resid[off]. Tile BM x 128, BK=64, 4 waves, 16x16x32 bf16 MFMA.
template<int WM, int GATHER, int CIN, int RES, int OMODE, int AF32>
__global__ __launch_bounds__(256, 2)
void gemm_kernel(const void* __restrict__ A, const u16* __restrict__ Bt,
                 const int* __restrict__ neigh, const float* __restrict__ bias,
                 const float* __restrict__ resid, void* __restrict__ out,
                 u16* __restrict__ out2, const u16* __restrict__ zbuf,
                 const int Mvalid, const int Ktot, const int Nin)
{
    constexpr int BM  = 2 * WM;
    constexpr int FM  = WM / 16;
    constexpr int ITA = BM / 32;
    __shared__ u16 lA[BM * 64];
    __shared__ u16 lB[128 * 64];
    const int tid  = threadIdx.x;
    const int wave = tid >> 6, lane = tid & 63;
    const int wr = wave >> 1, wc = wave & 1;
    const int quad = lane >> 4, l16 = lane & 15;
    const int mBase = blockIdx.x * BM;
    const int nBase = blockIdx.y * 128;

    f32x4 acc[FM][4];
    #pragma unroll
    for (int i = 0; i < FM; ++i)
        #pragma unroll
        for (int j = 0; j < 4; ++j)
            acc[i][j] = (f32x4){0.f, 0.f, 0.f, 0.f};

    for (int k0 = 0; k0 < Ktot; k0 += 64) {
        f32x4 va[ITA], vb[4];
        #pragma unroll
        for (int it = 0; it < ITA; ++it) {
            const int chunk = (wave * ITA + it) * 64 + lane;
            const int row   = chunk >> 3;
            const int cofs  = (chunk & 7) * 8;
            const int gm    = mBase + row;
            if constexpr (GATHER) {
                const int j27 = k0 / CIN;
                const int cb  = k0 % CIN;
                const int idx = (gm < Mvalid) ? neigh[gm * 27 + j27] : -1;
                const u16* src = ((u32)idx < (u32)Nin)
                    ? ((const u16*)A + (size_t)idx * CIN + cb + cofs) : (zbuf + cofs);
                va[it] = *(const f32x4*)src;
            } else if constexpr (AF32) {
                const float* src = (gm < Mvalid)
                    ? ((const float*)A + (size_t)gm * Ktot + k0 + cofs)
                    : ((const float*)zbuf + cofs);
                const f32x4 lo = ((const f32x4*)src)[0];
                const f32x4 hi = ((const f32x4*)src)[1];
                u32 w4[4] = { pack2(lo[0],lo[1]), pack2(lo[2],lo[3]),
                              pack2(hi[0],hi[1]), pack2(hi[2],hi[3]) };
                va[it] = *(const f32x4*)w4;
            } else {
                const u16* src = (gm < Mvalid)
                    ? ((const u16*)A + (size_t)gm * Ktot + k0 + cofs) : (zbuf + cofs);
                va[it] = *(const f32x4*)src;
            }
        }
        #pragma unroll
        for (int it = 0; it < 4; ++it) {
            const int chunk = (wave * 4 + it) * 64 + lane;
            const int row   = chunk >> 3;
            const int cofs  = (chunk & 7) * 8;
            vb[it] = *(const f32x4*)(Bt + (size_t)(nBase + row) * Ktot + k0 + cofs);
        }
        __syncthreads();   // prior compute done before overwrite
        #pragma unroll
        for (int it = 0; it < ITA; ++it) {
            const int chunk = (wave * ITA + it) * 64 + lane;
            *(f32x4*)&lA[chunk * 8] = va[it];
        }
        #pragma unroll
        for (int it = 0; it < 4; ++it) {
            const int chunk = (wave * 4 + it) * 64 + lane;
            *(f32x4*)&lB[chunk * 8] = vb[it];
        }
        __syncthreads();
        #pragma unroll
        for (int kk = 0; kk < 64; kk += 32) {
            bf16x8 bfr[4], af[FM];
            #pragma unroll
            for (int j = 0; j < 4; ++j)
                bfr[j] = ldfrag(&lB[(wc*64 + j*16 + l16) * 64 + kk + quad*8]);
            #pragma unroll
            for (int i = 0; i < FM; ++i)
                af[i] = ldfrag(&lA[(wr*WM + i*16 + l16) * 64 + kk + quad*8]);
            #pragma unroll
            for (int i = 0; i < FM; ++i)
                #pragma unroll
                for (int j = 0; j < 4; ++j)
                    acc[i][j] = __builtin_amdgcn_mfma_f32_16x16x32_bf16(af[i], bfr[j], acc[i][j], 0, 0, 0);
        }
    }
    // epilogue: D[row=quad*4+r][col=l16]
    #pragma unroll
    for (int j = 0; j < 4; ++j) {
        const int col = nBase + wc*64 + j*16 + l16;
        const float bv = bias[col];
        #pragma unroll
        for (int i = 0; i < FM; ++i) {
            const int row0 = mBase + wr*WM + i*16 + quad*4;
            #pragma unroll
            for (int r = 0; r < 4; ++r) {
                const int row = row0 + r;
                if (row < Mvalid) {
                    float v = acc[i][j][r] + bv;
                    const size_t off = (size_t)row * 256 + col;
                    if constexpr (RES) v += resid[off];
                    if constexpr (OMODE == 0) ((u16*)out)[off] = f2bf(v);
                    else {
                        ((float*)out)[off] = v;
                        if constexpr (OMODE == 2) out2[off] = f2bf(v);
                    }
                }
            }
        }
    }
}

extern "C" void kernel_launch(void* const* d_in, const int* in_sizes, int n_in,
                              void* d_out, int out_size, void* d_ws, size_t ws_size,
                              hipStream_t stream)
{
    // fp32 inputs (per reference dtypes); int32 neighbor tables; fp32 OUTPUTS
    const float* x    = (const float*)d_in[0];
    const float* ctx  = (const float*)d_in[1];
    const int* neigh  = (const int*)d_in[2];
    const int* neighd = (const int*)d_in[3];
    const float* g1w = (const float*)d_in[4];
    const float* g1b = (const float*)d_in[5];
    const float* w1  = (const float*)d_in[6];
    const float* b1  = (const float*)d_in[7];
    const float* g2w = (const float*)d_in[8];
    const float* g2b = (const float*)d_in[9];
    const float* w2  = (const float*)d_in[10];
    const float* b2  = (const float*)d_in[11];
    const float* scw = (const float*)d_in[12];
    const float* scb = (const float*)d_in[13];
    const float* lnw = (const float*)d_in[14];
    const float* lnb = (const float*)d_in[15];
    const float* wq  = (const float*)d_in[16];
    const float* bq  = (const float*)d_in[17];
    const float* wk  = (const float*)d_in[18];
    const float* bk  = (const float*)d_in[19];
    const float* wv  = (const float*)d_in[20];
    const float* bv  = (const float*)d_in[21];
    const float* wo  = (const float*)d_in[22];
    const float* bo  = (const float*)d_in[23];
    const float* dw  = (const float*)d_in[24];
    const float* db  = (const float*)d_in[25];

    // fp32 output regions: x_down [2048,256] then h [16384,256]
    float* out0 = (float*)d_out;
    float* H5   = (float*)d_out + (size_t)2048 * 256;   // h region: sc -> h5 -> h (fp32)
    // transient scratch inside x_down region (dead until final down-conv)
    float* KF   = (float*)d_out;                        // 308*256 floats
    float* VF   = KF + (size_t)308 * 256;               // total 616 KB < 2 MB region

    // workspace (~20.6 MB)
    char* p = (char*)d_ws;
    auto alloc = [&](size_t bytes) { char* r = p; p += (bytes + 255) & ~(size_t)255; return r; };
    u16* zbuf = (u16*)alloc(512);
    u16* S0   = (u16*)alloc((size_t)16384*256*2);   // bf16: h1 / h3 / xn / o
    u16* S3   = (u16*)alloc((size_t)16384*256*2);   // bf16: h2 / q / h6
    u16* WtB  = (u16*)alloc((size_t)27*256*256*2);  // reused: Wt1 -> Wt2 -> WtD
    u16* scT  = (u16*)alloc((size_t)128*256*2);
    u16* wqT  = (u16*)alloc((size_t)256*256*2);
    u16* wkT  = (u16*)alloc((size_t)768*256*2);
    u16* wvT  = (u16*)alloc((size_t)768*256*2);
    u16* woT  = (u16*)alloc((size_t)256*256*2);

    zero_kernel<<<1, 128, 0, stream>>>((u32*)zbuf);
    transpose_one<<<dim3(8,4),   256, 0, stream>>>(scw, scT, 128);
    transpose_one<<<dim3(8,8),   256, 0, stream>>>(wq,  wqT, 256);
    transpose_one<<<dim3(8,24),  256, 0, stream>>>(wk,  wkT, 768);
    transpose_one<<<dim3(8,24),  256, 0, stream>>>(wv,  wvT, 768);
    transpose_one<<<dim3(8,8),   256, 0, stream>>>(wo,  woT, 256);
    transpose_one<<<dim3(8,108), 256, 0, stream>>>(w1,  WtB, 3456);

    // ResnetBlock
    gn_silu_kernel<128,4,1><<<128, 256, 0, stream>>>(x, g1w, g1b, S0);
    gemm_kernel<64,1,128,0,0,0><<<dim3(128,2), 256, 0, stream>>>(S0, WtB, neigh, b1, nullptr, S3, nullptr, zbuf, 16384, 3456, 16384);
    gn_silu_kernel<256,8,0><<<128, 256, 0, stream>>>(S3, g2w, g2b, S0);
    // shortcut: sc = x @ scT + scb -> H5 fp32 (in d_out h region)
    gemm_kernel<64,0,1,0,1,1><<<dim3(128,2), 256, 0, stream>>>(x, scT, nullptr, scb, nullptr, H5, nullptr, zbuf, 16384, 128, 0);
    transpose_one<<<dim3(8,216), 256, 0, stream>>>(w2, WtB, 6912);
    // conv2 + residual in-place fp32: h5 = conv(h3) + b2 + sc
    gemm_kernel<64,1,256,1,1,0><<<dim3(128,2), 256, 0, stream>>>(S0, WtB, neigh, b2, H5, H5, nullptr, zbuf, 16384, 6912, 16384);
    // CrossAttention
    ln_kernel<<<4096, 256, 0, stream>>>(H5, lnw, lnb, S0);
    gemm_kernel<64,0,1,0,0,0><<<dim3(128,2), 256, 0, stream>>>(S0, wqT, nullptr, bq, nullptr, S3, nullptr, zbuf, 16384, 256, 0);
    gemm_kernel<64,0,1,0,1,1><<<dim3(3,2),   256, 0, stream>>>(ctx, wkT, nullptr, bk, nullptr, KF, nullptr, zbuf, 308, 768, 0);
    gemm_kernel<64,0,1,0,1,1><<<dim3(3,2),   256, 0, stream>>>(ctx, wvT, nullptr, bv, nullptr, VF, nullptr, zbuf, 308, 768, 0);
    attn_kernel<<<dim3(16,4,8), 256, 0, stream>>>(S3, KF, VF, S0);
    // h = h5 + o @ woT + bo -> fp32 H5 (output 1) + bf16 copy S3 for down-conv
    gemm_kernel<64,0,1,1,2,0><<<dim3(128,2), 256, 0, stream>>>(S0, woT, nullptr, bo, H5, H5, S3, zbuf, 16384, 256, 0);
    // down conv (output 0, fp32; KF/VF region now dead)
    transpose_one<<<dim3(8,216), 256, 0, stream>>>(dw, WtB, 6912);
    gemm_kernel<16,1,256,0,1,0><<<dim3(64,2), 256, 0, stream>>>(S3, WtB, neighd, db, nullptr, out0, nullptr, zbuf, 2048, 6912, 16384);
}

// Round 7
// 707.930 us; speedup vs baseline: 1.2466x; 1.2466x over previous
//
#include <hip/hip_runtime.h>
#include <stdint.h>

typedef unsigned short u16;
typedef unsigned int   u32;
typedef __attribute__((ext_vector_type(8))) __bf16 bf16x8;
typedef __attribute__((ext_vector_type(4))) float  f32x4;

__device__ __forceinline__ float bflo(u32 u){ return __uint_as_float(u << 16); }
__device__ __forceinline__ float bfhi(u32 u){ return __uint_as_float(u & 0xffff0000u); }
__device__ __forceinline__ float bf2f(u16 v){ return __uint_as_float(((u32)v) << 16); }
__device__ __forceinline__ u16 f2bf(float f){ u32 u = __float_as_uint(f);
    return (u16)((u + 0x7fffu + ((u >> 16) & 1u)) >> 16); }
__device__ __forceinline__ u32 pack2(float a, float b){ return (u32)f2bf(a) | ((u32)f2bf(b) << 16); }

union ABu { f32x4 f; bf16x8 b; };
__device__ __forceinline__ bf16x8 ldfrag(const u16* p){ ABu u; u.f = *(const f32x4*)p; return u.b; }

// ---------------- zero fill (zbuf: 512 B of zeros for masked rows) ----------
__global__ void zero_kernel(u32* p){ p[threadIdx.x] = 0u; }

// ---------------- bias init for split-K output ------------------------------
__global__ __launch_bounds__(256) void bias_init(float* out, const float* b)
{ out[(size_t)blockIdx.x * 256 + threadIdx.x] = b[threadIdx.x]; }

// -------- transpose one weight: fp32 [R,256] -> bf16 [256,R] ----------------
__global__ __launch_bounds__(256)
void transpose_one(const float* __restrict__ in, u16* __restrict__ out, int R)
{
    const int r0 = blockIdx.y * 32, c0 = blockIdx.x * 32;
    __shared__ u16 t[32][33];
    const int tx = threadIdx.x & 31, ty = threadIdx.x >> 5;
    #pragma unroll
    for (int i = 0; i < 4; ++i)
        t[ty + i*8][tx] = f2bf(in[(size_t)(r0 + ty + i*8) * 256 + c0 + tx]);
    __syncthreads();
    #pragma unroll
    for (int i = 0; i < 4; ++i)
        out[(size_t)(c0 + ty + i*8) * R + r0 + tx] = t[tx][ty + i*8];
}

// -------- group norm (per sample, per group) + SiLU; IF32 = fp32 input ------
template<int C, int CPG, int IF32>
__global__ __launch_bounds__(256)
void gn_silu_kernel(const void* __restrict__ xv, const float* __restrict__ gw,
                    const float* __restrict__ gb, u16* __restrict__ y)
{
    const int b = blockIdx.x >> 5, g = blockIdx.x & 31;
    const size_t base = (size_t)b * 4096 * C + g * CPG;
    float s = 0.f, ss = 0.f;
    for (int p = threadIdx.x; p < 4096; p += 256) {
        if constexpr (IF32) {
            const float* rp = (const float*)xv + base + (size_t)p * C;
            #pragma unroll
            for (int c = 0; c < CPG; ++c) { const float v = rp[c]; s += v; ss += v*v; }
        } else {
            const u32* rp = (const u32*)((const u16*)xv + base + (size_t)p * C);
            #pragma unroll
            for (int c = 0; c < CPG/2; ++c) {
                const u32 u = rp[c];
                const float v0 = bflo(u), v1 = bfhi(u);
                s += v0 + v1; ss += v0*v0 + v1*v1;
            }
        }
    }
    __shared__ float sbuf[8];
    const int wave = threadIdx.x >> 6, lane = threadIdx.x & 63;
    #pragma unroll
    for (int o = 32; o > 0; o >>= 1) { s += __shfl_down(s, o); ss += __shfl_down(ss, o); }
    if (lane == 0) { sbuf[wave] = s; sbuf[4 + wave] = ss; }
    __syncthreads();
    s  = sbuf[0] + sbuf[1] + sbuf[2] + sbuf[3];
    ss = sbuf[4] + sbuf[5] + sbuf[6] + sbuf[7];
    constexpr float invn = 1.f / (4096.f * CPG);
    const float mean = s * invn;
    const float rstd = rsqrtf(ss * invn - mean * mean + 1e-5f);
    float ga[CPG], be[CPG];
    #pragma unroll
    for (int c = 0; c < CPG; ++c) { ga[c] = gw[g*CPG + c] * rstd; be[c] = gb[g*CPG + c]; }
    for (int p = threadIdx.x; p < 4096; p += 256) {
        u32* wp = (u32*)(y + base + (size_t)p * C);
        float v[CPG];
        if constexpr (IF32) {
            const float* rp = (const float*)xv + base + (size_t)p * C;
            #pragma unroll
            for (int c = 0; c < CPG; ++c) v[c] = rp[c];
        } else {
            const u32* rp = (const u32*)((const u16*)xv + base + (size_t)p * C);
            #pragma unroll
            for (int c = 0; c < CPG/2; ++c) { const u32 u = rp[c]; v[2*c] = bflo(u); v[2*c+1] = bfhi(u); }
        }
        #pragma unroll
        for (int c = 0; c < CPG/2; ++c) {
            float v0 = (v[2*c]   - mean) * ga[2*c]   + be[2*c];
            float v1 = (v[2*c+1] - mean) * ga[2*c+1] + be[2*c+1];
            v0 = v0 / (1.f + __expf(-v0));
            v1 = v1 / (1.f + __expf(-v1));
            wp[c] = pack2(v0, v1);
        }
    }
}

// ---------------- layer norm (fp32 in, fp32 params) -> bf16 out -------------
__global__ __launch_bounds__(256)
void ln_kernel(const float* __restrict__ h, const float* __restrict__ w,
               const float* __restrict__ b, u16* __restrict__ y)
{
    const int row = blockIdx.x * 4 + (threadIdx.x >> 6);
    const int lane = threadIdx.x & 63;
    const f32x4 v = *(const f32x4*)(h + (size_t)row * 256 + lane * 4);
    float s  = v[0] + v[1] + v[2] + v[3];
    float ss = v[0]*v[0] + v[1]*v[1] + v[2]*v[2] + v[3]*v[3];
    #pragma unroll
    for (int o = 32; o > 0; o >>= 1) { s += __shfl_down(s, o); ss += __shfl_down(ss, o); }
    s = __shfl(s, 0); ss = __shfl(ss, 0);
    const float mean = s * (1.f/256.f);
    const float rstd = rsqrtf(ss * (1.f/256.f) - mean*mean + 1e-5f);
    const int c = lane * 4;
    const float o0 = (v[0]-mean)*rstd*w[c+0] + b[c+0];
    const float o1 = (v[1]-mean)*rstd*w[c+1] + b[c+1];
    const float o2 = (v[2]-mean)*rstd*w[c+2] + b[c+2];
    const float o3 = (v[3]-mean)*rstd*w[c+3] + b[c+3];
    u32* wp = (u32*)(y + (size_t)row * 256 + c);
    wp[0] = pack2(o0, o1); wp[1] = pack2(o2, o3);
}

// -------- cross attention: block = (h, b, p-chunk of 512 rows) --------------
__global__ __launch_bounds__(256)
void attn_kernel(const u16* __restrict__ q, const float* __restrict__ kf,
                 const float* __restrict__ vf, u16* __restrict__ o)
{
    const int h = blockIdx.x, b = blockIdx.y, pc = blockIdx.z;
    __shared__ float kS[77*16], vS[77*16];
    for (int i = threadIdx.x; i < 77*16; i += 256) {
        const int l = i >> 4, d = i & 15;
        const size_t src = (size_t)(b*77 + l) * 256 + h*16 + d;
        kS[i] = kf[src];
        vS[i] = vf[src];
    }
    __syncthreads();
    for (int p = pc*512 + threadIdx.x; p < pc*512 + 512; p += 256) {
        const size_t row = (size_t)b * 4096 + p;
        const u32* qp = (const u32*)(q + row * 256 + h * 16);
        float qv[16];
        #pragma unroll
        for (int d2 = 0; d2 < 8; ++d2) { const u32 u = qp[d2]; qv[2*d2] = bflo(u); qv[2*d2+1] = bfhi(u); }
        float m = -1e30f;
        for (int l = 0; l < 77; ++l) {
            float sc = 0.f;
            #pragma unroll
            for (int d = 0; d < 16; ++d) sc += qv[d] * kS[l*16 + d];
            m = fmaxf(m, sc);
        }
        float ssum = 0.f, oacc[16];
        #pragma unroll
        for (int d = 0; d < 16; ++d) oacc[d] = 0.f;
        for (int l = 0; l < 77; ++l) {
            float sc = 0.f;
            #pragma unroll
            for (int d = 0; d < 16; ++d) sc += qv[d] * kS[l*16 + d];
            const float pw = __expf((sc - m) * 0.25f);   // 1/sqrt(16)
            ssum += pw;
            #pragma unroll
            for (int d = 0; d < 16; ++d) oacc[d] += pw * vS[l*16 + d];
        }
        const float inv = 1.f / ssum;
        u32* op = (u32*)(o + row * 256 + h * 16);
        #pragma unroll
        for (int d2 = 0; d2 < 8; ++d2) op[d2] = pack2(oacc[2*d2]*inv, oacc[2*d2+1]*inv);
    }
}

// ---------------- MFMA GEMM: C[M,256] = A[M,Ktot] @ Bt[256,Ktot]^T ----------
// Tile BM=128 x BN=64, BK=64, 4 waves stacked in M (WM=32), XOR-swizzled LDS.
// GATHER: A row for K-block comes from bf16 A[neigh[m][k0/CIN]*CIN + k0%CIN];
// invalid idx -> zbuf. AF32: A fp32 -> bf16 during staging.
// OMODE: 0 = bf16 out; 1 = fp32 out; 2 = fp32 out + bf16 out2.
// SPLITK: blockIdx.z covers ksteps K-blocks; fp32 atomicAdd, no bias/resid.
template<int GATHER, int CIN, int RES, int OMODE, int AF32, int SPLITK>
__global__ __launch_bounds__(256, 2)
void gemm_kernel(const void* __restrict__ A, const u16* __restrict__ Bt,
                 const int* __restrict__ neigh, const float* __restrict__ bias,
                 const float* __restrict__ resid, void* __restrict__ out,
                 u16* __restrict__ out2, const u16* __restrict__ zbuf,
                 const int Mvalid, const int Ktot, const int Nin, const int ksteps)
{
    __shared__ u16 lA[128 * 64];
    __shared__ u16 lB[64 * 64];
    const int tid  = threadIdx.x;
    const int wave = tid >> 6, lane = tid & 63;
    const int quad = lane >> 4, l16 = lane & 15;
    const int mBase = blockIdx.x * 128;
    const int nBase = blockIdx.y * 64;
    const int kbeg = SPLITK ? blockIdx.z * ksteps * 64 : 0;
    const int kend = SPLITK ? kbeg + ksteps * 64 : Ktot;

    f32x4 acc[2][4];
    #pragma unroll
    for (int i = 0; i < 2; ++i)
        #pragma unroll
        for (int j = 0; j < 4; ++j)
            acc[i][j] = (f32x4){0.f, 0.f, 0.f, 0.f};

    for (int k0 = kbeg; k0 < kend; k0 += 64) {
        f32x4 va[4], vb[2];
        #pragma unroll
        for (int it = 0; it < 4; ++it) {           // A tile: 128 rows x 64 k
            const int chunk = (wave * 4 + it) * 64 + lane;
            const int row   = chunk >> 3;
            const int cofs  = (chunk & 7) * 8;
            const int gm    = mBase + row;
            if constexpr (GATHER) {
                const int j27 = k0 / CIN;
                const int cb  = k0 % CIN;
                const int idx = (gm < Mvalid) ? neigh[gm * 27 + j27] : -1;
                const u16* src = ((u32)idx < (u32)Nin)
                    ? ((const u16*)A + (size_t)idx * CIN + cb + cofs) : (zbuf + cofs);
                va[it] = *(const f32x4*)src;
            } else if constexpr (AF32) {
                const float* src = (gm < Mvalid)
                    ? ((const float*)A + (size_t)gm * Ktot + k0 + cofs)
                    : ((const float*)zbuf + cofs);
                const f32x4 lo = ((const f32x4*)src)[0];
                const f32x4 hi = ((const f32x4*)src)[1];
                u32 w4[4] = { pack2(lo[0],lo[1]), pack2(lo[2],lo[3]),
                              pack2(hi[0],hi[1]), pack2(hi[2],hi[3]) };
                va[it] = *(const f32x4*)w4;
            } else {
                const u16* src = (gm < Mvalid)
                    ? ((const u16*)A + (size_t)gm * Ktot + k0 + cofs) : (zbuf + cofs);
                va[it] = *(const f32x4*)src;
            }
        }
        #pragma unroll
        for (int it = 0; it < 2; ++it) {           // B tile: 64 rows x 64 k
            const int chunk = (wave * 2 + it) * 64 + lane;
            const int row   = chunk >> 3;
            const int cofs  = (chunk & 7) * 8;
            vb[it] = *(const f32x4*)(Bt + (size_t)(nBase + row) * Ktot + k0 + cofs);
        }
        __syncthreads();   // prior compute done before overwrite
        #pragma unroll
        for (int it = 0; it < 4; ++it) {
            const int chunk = (wave * 4 + it) * 64 + lane;
            const int row = chunk >> 3, g = chunk & 7;
            *(f32x4*)&lA[row * 64 + ((g ^ (row & 7)) << 3)] = va[it];
        }
        #pragma unroll
        for (int it = 0; it < 2; ++it) {
            const int chunk = (wave * 2 + it) * 64 + lane;
            const int row = chunk >> 3, g = chunk & 7;
            *(f32x4*)&lB[row * 64 + ((g ^ (row & 7)) << 3)] = vb[it];
        }
        __syncthreads();
        #pragma unroll
        for (int kk2 = 0; kk2 < 2; ++kk2) {
            const int grp = (((quad + kk2 * 4) ^ (l16 & 7)) << 3);
            bf16x8 bfr[4], af[2];
            #pragma unroll
            for (int j = 0; j < 4; ++j)
                bfr[j] = ldfrag(&lB[(j*16 + l16) * 64 + grp]);
            #pragma unroll
            for (int i = 0; i < 2; ++i)
                af[i] = ldfrag(&lA[(wave*32 + i*16 + l16) * 64 + grp]);
            #pragma unroll
            for (int i = 0; i < 2; ++i)
                #pragma unroll
                for (int j = 0; j < 4; ++j)
                    acc[i][j] = __builtin_amdgcn_mfma_f32_16x16x32_bf16(af[i], bfr[j], acc[i][j], 0, 0, 0);
        }
    }
    // epilogue: D[row=quad*4+r][col=l16]
    #pragma unroll
    for (int j = 0; j < 4; ++j) {
        const int col = nBase + j*16 + l16;
        const float bv = SPLITK ? 0.f : bias[col];
        #pragma unroll
        for (int i = 0; i < 2; ++i) {
            const int row0 = mBase + wave*32 + i*16 + quad*4;
            #pragma unroll
            for (int r = 0; r < 4; ++r) {
                const int row = row0 + r;
                if (row < Mvalid) {
                    const size_t off = (size_t)row * 256 + col;
                    float v = acc[i][j][r] + bv;
                    if constexpr (SPLITK) {
                        atomicAdd((float*)out + off, v);
                    } else {
                        if constexpr (RES) v += resid[off];
                        if constexpr (OMODE == 0) ((u16*)out)[off] = f2bf(v);
                        else {
                            ((float*)out)[off] = v;
                            if constexpr (OMODE == 2) out2[off] = f2bf(v);
                        }
                    }
                }
            }
        }
    }
}

extern "C" void kernel_launch(void* const* d_in, const int* in_sizes, int n_in,
                              void* d_out, int out_size, void* d_ws, size_t ws_size,
                              hipStream_t stream)
{
    const float* x    = (const float*)d_in[0];
    const float* ctx  = (const float*)d_in[1];
    const int* neigh  = (const int*)d_in[2];
    const int* neighd = (const int*)d_in[3];
    const float* g1w = (const float*)d_in[4];
    const float* g1b = (const float*)d_in[5];
    const float* w1  = (const float*)d_in[6];
    const float* b1  = (const float*)d_in[7];
    const float* g2w = (const float*)d_in[8];
    const float* g2b = (const float*)d_in[9];
    const float* w2  = (const float*)d_in[10];
    const float* b2  = (const float*)d_in[11];
    const float* scw = (const float*)d_in[12];
    const float* scb = (const float*)d_in[13];
    const float* lnw = (const float*)d_in[14];
    const float* lnb = (const float*)d_in[15];
    const float* wq  = (const float*)d_in[16];
    const float* bq  = (const float*)d_in[17];
    const float* wk  = (const float*)d_in[18];
    const float* bk  = (const float*)d_in[19];
    const float* wv  = (const float*)d_in[20];
    const float* bv  = (const float*)d_in[21];
    const float* wo  = (const float*)d_in[22];
    const float* bo  = (const float*)d_in[23];
    const float* dw  = (const float*)d_in[24];
    const float* db  = (const float*)d_in[25];

    // fp32 output regions: x_down [2048,256] then h [16384,256]
    float* out0 = (float*)d_out;
    float* H5   = (float*)d_out + (size_t)2048 * 256;   // h region: sc -> h5 -> h
    float* KF   = (float*)d_out;                        // transient in x_down region
    float* VF   = KF + (size_t)308 * 256;

    // workspace (~20.6 MB)
    char* p = (char*)d_ws;
    auto alloc = [&](size_t bytes) { char* r = p; p += (bytes + 255) & ~(size_t)255; return r; };
    u16* zbuf = (u16*)alloc(512);
    u16* S0   = (u16*)alloc((size_t)16384*256*2);   // bf16: h1 / h3 / xn / o
    u16* S3   = (u16*)alloc((size_t)16384*256*2);   // bf16: h2 / q / h6
    u16* WtB  = (u16*)alloc((size_t)27*256*256*2);  // reused: Wt1 -> Wt2 -> WtD
    u16* scT  = (u16*)alloc((size_t)128*256*2);
    u16* wqT  = (u16*)alloc((size_t)256*256*2);
    u16* wkT  = (u16*)alloc((size_t)768*256*2);
    u16* wvT  = (u16*)alloc((size_t)768*256*2);
    u16* woT  = (u16*)alloc((size_t)256*256*2);

    zero_kernel<<<1, 128, 0, stream>>>((u32*)zbuf);
    transpose_one<<<dim3(8,4),   256, 0, stream>>>(scw, scT, 128);
    transpose_one<<<dim3(8,8),   256, 0, stream>>>(wq,  wqT, 256);
    transpose_one<<<dim3(8,24),  256, 0, stream>>>(wk,  wkT, 768);
    transpose_one<<<dim3(8,24),  256, 0, stream>>>(wv,  wvT, 768);
    transpose_one<<<dim3(8,8),   256, 0, stream>>>(wo,  woT, 256);
    transpose_one<<<dim3(8,108), 256, 0, stream>>>(w1,  WtB, 3456);

    // ResnetBlock
    gn_silu_kernel<128,4,1><<<128, 256, 0, stream>>>(x, g1w, g1b, S0);
    gemm_kernel<1,128,0,0,0,0><<<dim3(128,4), 256, 0, stream>>>(S0, WtB, neigh, b1, nullptr, S3, nullptr, zbuf, 16384, 3456, 16384, 0);
    gn_silu_kernel<256,8,0><<<128, 256, 0, stream>>>(S3, g2w, g2b, S0);
    // shortcut: sc = x @ scT + scb -> H5 fp32
    gemm_kernel<0,1,0,1,1,0><<<dim3(128,4), 256, 0, stream>>>(x, scT, nullptr, scb, nullptr, H5, nullptr, zbuf, 16384, 128, 0, 0);
    transpose_one<<<dim3(8,216), 256, 0, stream>>>(w2, WtB, 6912);
    // conv2 + residual in-place fp32: h5 = conv(h3) + b2 + sc
    gemm_kernel<1,256,1,1,0,0><<<dim3(128,4), 256, 0, stream>>>(S0, WtB, neigh, b2, H5, H5, nullptr, zbuf, 16384, 6912, 16384, 0);
    // CrossAttention
    ln_kernel<<<4096, 256, 0, stream>>>(H5, lnw, lnb, S0);
    gemm_kernel<0,1,0,0,0,0><<<dim3(128,4), 256, 0, stream>>>(S0, wqT, nullptr, bq, nullptr, S3, nullptr, zbuf, 16384, 256, 0, 0);
    gemm_kernel<0,1,0,1,1,0><<<dim3(3,4),   256, 0, stream>>>(ctx, wkT, nullptr, bk, nullptr, KF, nullptr, zbuf, 308, 768, 0, 0);
    gemm_kernel<0,1,0,1,1,0><<<dim3(3,4),   256, 0, stream>>>(ctx, wvT, nullptr, bv, nullptr, VF, nullptr, zbuf, 308, 768, 0, 0);
    attn_kernel<<<dim3(16,4,8), 256, 0, stream>>>(S3, KF, VF, S0);
    // h = h5 + o @ woT + bo -> fp32 H5 (output 1) + bf16 copy S3 for down-conv
    gemm_kernel<0,1,1,2,0,0><<<dim3(128,4), 256, 0, stream>>>(S0, woT, nullptr, bo, H5, H5, S3, zbuf, 16384, 256, 0, 0);
    // down conv (output 0, fp32): init with bias, then split-K=6 atomic accumulate
    transpose_one<<<dim3(8,216), 256, 0, stream>>>(dw, WtB, 6912);
    bias_init<<<2048, 256, 0, stream>>>(out0, db);
    gemm_kernel<1,256,0,1,0,1><<<dim3(16,4,6), 256, 0, stream>>>(S3, WtB, neighd, nullptr, nullptr, out0, nullptr, zbuf, 2048, 6912, 16384, 18);
}

// Round 8
// 547.097 us; speedup vs baseline: 1.6131x; 1.2940x over previous
//
#include <hip/hip_runtime.h>
#include <stdint.h>

typedef unsigned short u16;
typedef unsigned int   u32;
typedef __attribute__((ext_vector_type(8))) __bf16 bf16x8;
typedef __attribute__((ext_vector_type(4))) float  f32x4;

__device__ __forceinline__ float bflo(u32 u){ return __uint_as_float(u << 16); }
__device__ __forceinline__ float bfhi(u32 u){ return __uint_as_float(u & 0xffff0000u); }
__device__ __forceinline__ float bf2f(u16 v){ return __uint_as_float(((u32)v) << 16); }
__device__ __forceinline__ u16 f2bf(float f){ u32 u = __float_as_uint(f);
    return (u16)((u + 0x7fffu + ((u >> 16) & 1u)) >> 16); }
__device__ __forceinline__ u32 pack2(float a, float b){ return (u32)f2bf(a) | ((u32)f2bf(b) << 16); }

union ABu { f32x4 f; bf16x8 b; };
__device__ __forceinline__ bf16x8 ldfrag(const u16* p){ ABu u; u.f = *(const f32x4*)p; return u.b; }

// ---------------- zero fill (zbuf: 512 B of zeros for masked rows) ----------
__global__ void zero_kernel(u32* p){ p[threadIdx.x] = 0u; }

// ---------------- bias init for split-K outputs -----------------------------
__global__ __launch_bounds__(256) void bias_init(float* out, const float* b)
{ out[(size_t)blockIdx.x * 256 + threadIdx.x] = b[threadIdx.x]; }

// -------- transpose one weight: fp32 [R,256] -> bf16 [256,R] ----------------
__global__ __launch_bounds__(256)
void transpose_one(const float* __restrict__ in, u16* __restrict__ out, int R)
{
    const int r0 = blockIdx.y * 32, c0 = blockIdx.x * 32;
    __shared__ u16 t[32][33];
    const int tx = threadIdx.x & 31, ty = threadIdx.x >> 5;
    #pragma unroll
    for (int i = 0; i < 4; ++i)
        t[ty + i*8][tx] = f2bf(in[(size_t)(r0 + ty + i*8) * 256 + c0 + tx]);
    __syncthreads();
    #pragma unroll
    for (int i = 0; i < 4; ++i)
        out[(size_t)(c0 + ty + i*8) * R + r0 + tx] = t[tx][ty + i*8];
}

// -------- group norm (per sample, per group) + SiLU; IF32 = fp32 input ------
template<int C, int CPG, int IF32>
__global__ __launch_bounds__(256)
void gn_silu_kernel(const void* __restrict__ xv, const float* __restrict__ gw,
                    const float* __restrict__ gb, u16* __restrict__ y)
{
    const int b = blockIdx.x >> 5, g = blockIdx.x & 31;
    const size_t base = (size_t)b * 4096 * C + g * CPG;
    float s = 0.f, ss = 0.f;
    for (int p = threadIdx.x; p < 4096; p += 256) {
        if constexpr (IF32) {
            const float* rp = (const float*)xv + base + (size_t)p * C;
            #pragma unroll
            for (int c = 0; c < CPG; ++c) { const float v = rp[c]; s += v; ss += v*v; }
        } else {
            const u32* rp = (const u32*)((const u16*)xv + base + (size_t)p * C);
            #pragma unroll
            for (int c = 0; c < CPG/2; ++c) {
                const u32 u = rp[c];
                const float v0 = bflo(u), v1 = bfhi(u);
                s += v0 + v1; ss += v0*v0 + v1*v1;
            }
        }
    }
    __shared__ float sbuf[8];
    const int wave = threadIdx.x >> 6, lane = threadIdx.x & 63;
    #pragma unroll
    for (int o = 32; o > 0; o >>= 1) { s += __shfl_down(s, o); ss += __shfl_down(ss, o); }
    if (lane == 0) { sbuf[wave] = s; sbuf[4 + wave] = ss; }
    __syncthreads();
    s  = sbuf[0] + sbuf[1] + sbuf[2] + sbuf[3];
    ss = sbuf[4] + sbuf[5] + sbuf[6] + sbuf[7];
    constexpr float invn = 1.f / (4096.f * CPG);
    const float mean = s * invn;
    const float rstd = rsqrtf(ss * invn - mean * mean + 1e-5f);
    float ga[CPG], be[CPG];
    #pragma unroll
    for (int c = 0; c < CPG; ++c) { ga[c] = gw[g*CPG + c] * rstd; be[c] = gb[g*CPG + c]; }
    for (int p = threadIdx.x; p < 4096; p += 256) {
        u32* wp = (u32*)(y + base + (size_t)p * C);
        float v[CPG];
        if constexpr (IF32) {
            const float* rp = (const float*)xv + base + (size_t)p * C;
            #pragma unroll
            for (int c = 0; c < CPG; ++c) v[c] = rp[c];
        } else {
            const u32* rp = (const u32*)((const u16*)xv + base + (size_t)p * C);
            #pragma unroll
            for (int c = 0; c < CPG/2; ++c) { const u32 u = rp[c]; v[2*c] = bflo(u); v[2*c+1] = bfhi(u); }
        }
        #pragma unroll
        for (int c = 0; c < CPG/2; ++c) {
            float v0 = (v[2*c]   - mean) * ga[2*c]   + be[2*c];
            float v1 = (v[2*c+1] - mean) * ga[2*c+1] + be[2*c+1];
            v0 = v0 / (1.f + __expf(-v0));
            v1 = v1 / (1.f + __expf(-v1));
            wp[c] = pack2(v0, v1);
        }
    }
}

// ---------------- layer norm (fp32 in, fp32 params) -> bf16 out -------------
__global__ __launch_bounds__(256)
void ln_kernel(const float* __restrict__ h, const float* __restrict__ w,
               const float* __restrict__ b, u16* __restrict__ y)
{
    const int row = blockIdx.x * 4 + (threadIdx.x >> 6);
    const int lane = threadIdx.x & 63;
    const f32x4 v = *(const f32x4*)(h + (size_t)row * 256 + lane * 4);
    float s  = v[0] + v[1] + v[2] + v[3];
    float ss = v[0]*v[0] + v[1]*v[1] + v[2]*v[2] + v[3]*v[3];
    #pragma unroll
    for (int o = 32; o > 0; o >>= 1) { s += __shfl_down(s, o); ss += __shfl_down(ss, o); }
    s = __shfl(s, 0); ss = __shfl(ss, 0);
    const float mean = s * (1.f/256.f);
    const float rstd = rsqrtf(ss * (1.f/256.f) - mean*mean + 1e-5f);
    const int c = lane * 4;
    const float o0 = (v[0]-mean)*rstd*w[c+0] + b[c+0];
    const float o1 = (v[1]-mean)*rstd*w[c+1] + b[c+1];
    const float o2 = (v[2]-mean)*rstd*w[c+2] + b[c+2];
    const float o3 = (v[3]-mean)*rstd*w[c+3] + b[c+3];
    u32* wp = (u32*)(y + (size_t)row * 256 + c);
    wp[0] = pack2(o0, o1); wp[1] = pack2(o2, o3);
}

// -------- cross attention: block = (h, b, p-chunk of 512 rows) --------------
__global__ __launch_bounds__(256)
void attn_kernel(const u16* __restrict__ q, const float* __restrict__ kf,
                 const float* __restrict__ vf, u16* __restrict__ o)
{
    const int h = blockIdx.x, b = blockIdx.y, pc = blockIdx.z;
    __shared__ float kS[77*16], vS[77*16];
    for (int i = threadIdx.x; i < 77*16; i += 256) {
        const int l = i >> 4, d = i & 15;
        const size_t src = (size_t)(b*77 + l) * 256 + h*16 + d;
        kS[i] = kf[src];
        vS[i] = vf[src];
    }
    __syncthreads();
    for (int p = pc*512 + threadIdx.x; p < pc*512 + 512; p += 256) {
        const size_t row = (size_t)b * 4096 + p;
        const u32* qp = (const u32*)(q + row * 256 + h * 16);
        float qv[16];
        #pragma unroll
        for (int d2 = 0; d2 < 8; ++d2) { const u32 u = qp[d2]; qv[2*d2] = bflo(u); qv[2*d2+1] = bfhi(u); }
        float m = -1e30f;
        for (int l = 0; l < 77; ++l) {
            float sc = 0.f;
            #pragma unroll
            for (int d = 0; d < 16; ++d) sc += qv[d] * kS[l*16 + d];
            m = fmaxf(m, sc);
        }
        float ssum = 0.f, oacc[16];
        #pragma unroll
        for (int d = 0; d < 16; ++d) oacc[d] = 0.f;
        for (int l = 0; l < 77; ++l) {
            float sc = 0.f;
            #pragma unroll
            for (int d = 0; d < 16; ++d) sc += qv[d] * kS[l*16 + d];
            const float pw = __expf((sc - m) * 0.25f);   // 1/sqrt(16)
            ssum += pw;
            #pragma unroll
            for (int d = 0; d < 16; ++d) oacc[d] += pw * vS[l*16 + d];
        }
        const float inv = 1.f / ssum;
        u32* op = (u32*)(o + row * 256 + h * 16);
        #pragma unroll
        for (int d2 = 0; d2 < 8; ++d2) op[d2] = pack2(oacc[2*d2]*inv, oacc[2*d2+1]*inv);
    }
}

// ---------------- MFMA GEMM: C[M,256] = A[M,Ktot] @ Bt[256,Ktot]^T ----------
// Tile BM=128 x BN=64, BK=64, 4 waves stacked in M, XOR-swizzled LDS.
// Software pipeline: data prefetch 1 k-step ahead (register dbuf), neighbor
// indices 2 k-steps ahead (ping-pong, loop unrolled x2; requires EVEN k-steps).
// GATHER: A row from bf16 A[neigh[m][k0/CIN]*CIN + k0%CIN]; invalid -> zbuf.
// AF32: A fp32 -> bf16 during staging. OMODE: 0 bf16 out; 1 fp32; 2 fp32+bf16.
// SPLITK: blockIdx.z covers ksteps K-blocks; fp32 atomicAdd, no bias/resid.
template<int GATHER, int CIN, int RES, int OMODE, int AF32, int SPLITK>
__global__ __launch_bounds__(256, 4)
void gemm_kernel(const void* __restrict__ A, const u16* __restrict__ Bt,
                 const int* __restrict__ neigh, const float* __restrict__ bias,
                 const float* __restrict__ bias2, const float* __restrict__ resid,
                 void* __restrict__ out, u16* __restrict__ out2,
                 const u16* __restrict__ zbuf,
                 const int Mvalid, const int Ktot, const int Nin, const int ksteps)
{
    __shared__ u16 lA[128 * 64];
    __shared__ u16 lB[64 * 64];
    const int tid  = threadIdx.x;
    const int wave = tid >> 6, lane = tid & 63;
    const int quad = lane >> 4, l16 = lane & 15;
    const int mBase = blockIdx.x * 128;
    const int nBase = blockIdx.y * 64;
    const int kbeg = SPLITK ? blockIdx.z * ksteps * 64 : 0;
    const int kend = SPLITK ? kbeg + ksteps * 64 : Ktot;

    // staging geometry (constant per lane)
    int aCofs[4], gm4[4];
    #pragma unroll
    for (int it = 0; it < 4; ++it) {
        const int chunk = (wave * 4 + it) * 64 + lane;
        aCofs[it] = (chunk & 7) * 8;
        gm4[it]   = mBase + (chunk >> 3);
    }
    int bRow[2], bCofs[2];
    #pragma unroll
    for (int it = 0; it < 2; ++it) {
        const int chunk = (wave * 2 + it) * 64 + lane;
        bRow[it]  = nBase + (chunk >> 3);
        bCofs[it] = (chunk & 7) * 8;
    }

    auto issueIdx = [&](int k0, int* dst) {
        if constexpr (GATHER) {
            const int j27 = k0 / CIN;
            #pragma unroll
            for (int it = 0; it < 4; ++it)
                dst[it] = (gm4[it] < Mvalid) ? neigh[gm4[it] * 27 + j27] : -1;
        }
    };
    auto issueA = [&](int k0, const int* idx, f32x4* va) {
        #pragma unroll
        for (int it = 0; it < 4; ++it) {
            if constexpr (GATHER) {
                const int cb = k0 % CIN;
                const u16* src = ((u32)idx[it] < (u32)Nin)
                    ? ((const u16*)A + (size_t)idx[it] * CIN + cb + aCofs[it])
                    : (zbuf + aCofs[it]);
                va[it] = *(const f32x4*)src;
            } else if constexpr (AF32) {
                const float* src = (gm4[it] < Mvalid)
                    ? ((const float*)A + (size_t)gm4[it] * Ktot + k0 + aCofs[it])
                    : ((const float*)zbuf + aCofs[it]);
                const f32x4 lo = ((const f32x4*)src)[0];
                const f32x4 hi = ((const f32x4*)src)[1];
                u32 w4[4] = { pack2(lo[0],lo[1]), pack2(lo[2],lo[3]),
                              pack2(hi[0],hi[1]), pack2(hi[2],hi[3]) };
                va[it] = *(const f32x4*)w4;
            } else {
                const u16* src = (gm4[it] < Mvalid)
                    ? ((const u16*)A + (size_t)gm4[it] * Ktot + k0 + aCofs[it])
                    : (zbuf + aCofs[it]);
                va[it] = *(const f32x4*)src;
            }
        }
    };
    auto issueB = [&](int k0, f32x4* vb) {
        #pragma unroll
        for (int it = 0; it < 2; ++it)
            vb[it] = *(const f32x4*)(Bt + (size_t)bRow[it] * Ktot + k0 + bCofs[it]);
    };
    auto storeLDS = [&](const f32x4* va, const f32x4* vb) {
        #pragma unroll
        for (int it = 0; it < 4; ++it) {
            const int chunk = (wave * 4 + it) * 64 + lane;
            const int row = chunk >> 3, g = chunk & 7;
            *(f32x4*)&lA[row * 64 + ((g ^ (row & 7)) << 3)] = va[it];
        }
        #pragma unroll
        for (int it = 0; it < 2; ++it) {
            const int chunk = (wave * 2 + it) * 64 + lane;
            const int row = chunk >> 3, g = chunk & 7;
            *(f32x4*)&lB[row * 64 + ((g ^ (row & 7)) << 3)] = vb[it];
        }
    };

    f32x4 acc[2][4];
    #pragma unroll
    for (int i = 0; i < 2; ++i)
        #pragma unroll
        for (int j = 0; j < 4; ++j)
            acc[i][j] = (f32x4){0.f, 0.f, 0.f, 0.f};

    auto mfmaPhase = [&]() {
        #pragma unroll
        for (int kk2 = 0; kk2 < 2; ++kk2) {
            const int grp = (((quad + kk2 * 4) ^ (l16 & 7)) << 3);
            bf16x8 bfr[4], af[2];
            #pragma unroll
            for (int j = 0; j < 4; ++j)
                bfr[j] = ldfrag(&lB[(j*16 + l16) * 64 + grp]);
            #pragma unroll
            for (int i = 0; i < 2; ++i)
                af[i] = ldfrag(&lA[(wave*32 + i*16 + l16) * 64 + grp]);
            #pragma unroll
            for (int i = 0; i < 2; ++i)
                #pragma unroll
                for (int j = 0; j < 4; ++j)
                    acc[i][j] = __builtin_amdgcn_mfma_f32_16x16x32_bf16(af[i], bfr[j], acc[i][j], 0, 0, 0);
        }
    };

    // -------- pipeline: prologue --------
    int idxP[4], idxQ[4];
    f32x4 va[4], vb[2];
    issueIdx(kbeg, idxP);
    issueA(kbeg, idxP, va);
    issueB(kbeg, vb);
    issueIdx(kbeg + 64 < kend ? kbeg + 64 : kbeg, idxQ);

    for (int k0 = kbeg; k0 < kend; k0 += 128) {
        {   // even step: data(k0) in va/vb; next data uses idxQ; refill idxP
            __syncthreads();
            storeLDS(va, vb);
            __syncthreads();
            const int kn = k0 + 64  < kend ? k0 + 64  : k0;
            const int ki = k0 + 128 < kend ? k0 + 128 : kn;
            issueA(kn, idxQ, va);
            issueB(kn, vb);
            issueIdx(ki, idxP);
            mfmaPhase();
        }
        {   // odd step: data(k0+64) in va/vb; next data uses idxP; refill idxQ
            __syncthreads();
            storeLDS(va, vb);
            __syncthreads();
            const int k1 = k0 + 64;
            const int kn = k1 + 64  < kend ? k1 + 64  : k1;
            const int ki = k1 + 128 < kend ? k1 + 128 : kn;
            issueA(kn, idxP, va);
            issueB(kn, vb);
            issueIdx(ki, idxQ);
            mfmaPhase();
        }
    }

    // -------- epilogue: D[row=quad*4+r][col=l16] --------
    #pragma unroll
    for (int j = 0; j < 4; ++j) {
        const int col = nBase + j*16 + l16;
        float bv = 0.f;
        if constexpr (!SPLITK) { bv = bias[col]; if (bias2) bv += bias2[col]; }
        #pragma unroll
        for (int i = 0; i < 2; ++i) {
            const int row0 = mBase + wave*32 + i*16 + quad*4;
            #pragma unroll
            for (int r = 0; r < 4; ++r) {
                const int row = row0 + r;
                if (row < Mvalid) {
                    const size_t off = (size_t)row * 256 + col;
                    float v = acc[i][j][r] + bv;
                    if constexpr (SPLITK) {
                        atomicAdd((float*)out + off, v);
                    } else {
                        if constexpr (RES) v += resid[off];
                        if constexpr (OMODE == 0) ((u16*)out)[off] = f2bf(v);
                        else {
                            ((float*)out)[off] = v;
                            if constexpr (OMODE == 2) out2[off] = f2bf(v);
                        }
                    }
                }
            }
        }
    }
}

extern "C" void kernel_launch(void* const* d_in, const int* in_sizes, int n_in,
                              void* d_out, int out_size, void* d_ws, size_t ws_size,
                              hipStream_t stream)
{
    const float* x    = (const float*)d_in[0];
    const float* ctx  = (const float*)d_in[1];
    const int* neigh  = (const int*)d_in[2];
    const int* neighd = (const int*)d_in[3];
    const float* g1w = (const float*)d_in[4];
    const float* g1b = (const float*)d_in[5];
    const float* w1  = (const float*)d_in[6];
    const float* b1  = (const float*)d_in[7];
    const float* g2w = (const float*)d_in[8];
    const float* g2b = (const float*)d_in[9];
    const float* w2  = (const float*)d_in[10];
    const float* b2  = (const float*)d_in[11];
    const float* scw = (const float*)d_in[12];
    const float* scb = (const float*)d_in[13];
    const float* lnw = (const float*)d_in[14];
    const float* lnb = (const float*)d_in[15];
    const float* wq  = (const float*)d_in[16];
    const float* bq  = (const float*)d_in[17];
    const float* wk  = (const float*)d_in[18];
    const float* bk  = (const float*)d_in[19];
    const float* wv  = (const float*)d_in[20];
    const float* bv  = (const float*)d_in[21];
    const float* wo  = (const float*)d_in[22];
    const float* bo  = (const float*)d_in[23];
    const float* dw  = (const float*)d_in[24];
    const float* db  = (const float*)d_in[25];

    // fp32 output regions: x_down [2048,256] then h [16384,256]
    float* out0 = (float*)d_out;
    float* H5   = (float*)d_out + (size_t)2048 * 256;   // h region: h2(fp32) -> sc+b2 -> h5 -> h
    float* KF   = (float*)d_out;                        // transient in x_down region
    float* VF   = KF + (size_t)308 * 256;

    // workspace (~20.6 MB)
    char* p = (char*)d_ws;
    auto alloc = [&](size_t bytes) { char* r = p; p += (bytes + 255) & ~(size_t)255; return r; };
    u16* zbuf = (u16*)alloc(512);
    u16* S0   = (u16*)alloc((size_t)16384*256*2);   // bf16: h1 / h3 / xn / o
    u16* S3   = (u16*)alloc((size_t)16384*256*2);   // bf16: q / h6
    u16* WtB  = (u16*)alloc((size_t)27*256*256*2);  // reused: Wt1 -> Wt2 -> WtD
    u16* scT  = (u16*)alloc((size_t)128*256*2);
    u16* wqT  = (u16*)alloc((size_t)256*256*2);
    u16* wkT  = (u16*)alloc((size_t)768*256*2);
    u16* wvT  = (u16*)alloc((size_t)768*256*2);
    u16* woT  = (u16*)alloc((size_t)256*256*2);

    zero_kernel<<<1, 128, 0, stream>>>((u32*)zbuf);
    transpose_one<<<dim3(8,4),   256, 0, stream>>>(scw, scT, 128);
    transpose_one<<<dim3(8,8),   256, 0, stream>>>(wq,  wqT, 256);
    transpose_one<<<dim3(8,24),  256, 0, stream>>>(wk,  wkT, 768);
    transpose_one<<<dim3(8,24),  256, 0, stream>>>(wv,  wvT, 768);
    transpose_one<<<dim3(8,8),   256, 0, stream>>>(wo,  woT, 256);
    transpose_one<<<dim3(8,108), 256, 0, stream>>>(w1,  WtB, 3456);

    // ResnetBlock
    gn_silu_kernel<128,4,1><<<128, 256, 0, stream>>>(x, g1w, g1b, S0);
    // conv1 split-K=3 (18 k-steps each), fp32 accumulate into H5 (init = b1)
    bias_init<<<16384, 256, 0, stream>>>(H5, b1);
    gemm_kernel<1,128,0,1,0,1><<<dim3(128,4,3), 256, 0, stream>>>(S0, WtB, neigh, nullptr, nullptr, nullptr, H5, nullptr, zbuf, 16384, 3456, 16384, 18);
    gn_silu_kernel<256,8,1><<<128, 256, 0, stream>>>(H5, g2w, g2b, S0);
    // shortcut overwrites H5: sc = x @ scT + (scb + b2)
    gemm_kernel<0,1,0,1,1,0><<<dim3(128,4), 256, 0, stream>>>(x, scT, nullptr, scb, b2, nullptr, H5, nullptr, zbuf, 16384, 128, 0, 0);
    transpose_one<<<dim3(8,216), 256, 0, stream>>>(w2, WtB, 6912);
    // conv2 split-K=3 (36 k-steps each), atomic accumulate into H5
    gemm_kernel<1,256,0,1,0,1><<<dim3(128,4,3), 256, 0, stream>>>(S0, WtB, neigh, nullptr, nullptr, nullptr, H5, nullptr, zbuf, 16384, 6912, 16384, 36);
    // CrossAttention
    ln_kernel<<<4096, 256, 0, stream>>>(H5, lnw, lnb, S0);
    gemm_kernel<0,1,0,0,0,0><<<dim3(128,4), 256, 0, stream>>>(S0, wqT, nullptr, bq, nullptr, nullptr, S3, nullptr, zbuf, 16384, 256, 0, 0);
    gemm_kernel<0,1,0,1,1,0><<<dim3(3,4),   256, 0, stream>>>(ctx, wkT, nullptr, bk, nullptr, nullptr, KF, nullptr, zbuf, 308, 768, 0, 0);
    gemm_kernel<0,1,0,1,1,0><<<dim3(3,4),   256, 0, stream>>>(ctx, wvT, nullptr, bv, nullptr, nullptr, VF, nullptr, zbuf, 308, 768, 0, 0);
    attn_kernel<<<dim3(16,4,8), 256, 0, stream>>>(S3, KF, VF, S0);
    // h = h5 + o @ woT + bo -> fp32 H5 (output 1) + bf16 copy S3 for down-conv
    gemm_kernel<0,1,1,2,0,0><<<dim3(128,4), 256, 0, stream>>>(S0, woT, nullptr, bo, nullptr, H5, H5, S3, zbuf, 16384, 256, 0, 0);
    // down conv (output 0, fp32): init with bias, then split-K=6 atomic accumulate
    transpose_one<<<dim3(8,216), 256, 0, stream>>>(dw, WtB, 6912);
    bias_init<<<2048, 256, 0, stream>>>(out0, db);
    gemm_kernel<1,256,0,1,0,1><<<dim3(16,4,6), 256, 0, stream>>>(S3, WtB, neighd, nullptr, nullptr, nullptr, out0, nullptr, zbuf, 2048, 6912, 16384, 18);
}